// Round 17
// baseline (84.023 us; speedup 1.0000x reference)
//
#include <hip/hip_runtime.h>

// MultiHeadSelfAttention: B=4 N=2048 F=512 H=8 D=64, scale = 1/sqrt(512)
// Pipeline: fused cvt (x->f16 + W^T->f16), fused QKV GEMM (mfma f16,
// gload_lds staging, Q pre-scaled by log2e/sqrt(512), V stored TRANSPOSED
// [B][H][D][N], f16x4 V stores), flash attention on 32x32x16 MFMA with
// IN-BLOCK KV-SPLIT (512-thr blocks; waves 0-3 kv 0-1023, waves 4-7 kv
// 1024-2047 for the same 128 q-rows; subtiled LDS with chunk-XOR swizzle
// (2-way residual = free), pi row permutation so P=exp2(S) packs straight
// into PV A-frags, VALU denominators, fp32 partial combine through LDS),
// output GEMM (128x64, fp32+bias).
// ws: xb@0 | wt@8MB | Q@10MB K@18MB Vt@26MB | CX@34MB.

typedef _Float16 f16;
typedef _Float16 f16x2 __attribute__((ext_vector_type(2)));
typedef _Float16 f16x4 __attribute__((ext_vector_type(4)));
typedef _Float16 f16x8 __attribute__((ext_vector_type(8)));
typedef float f32x4 __attribute__((ext_vector_type(4)));
typedef float f32x16 __attribute__((ext_vector_type(16)));

#define MFMA16(a, b, c) __builtin_amdgcn_mfma_f32_16x16x32_f16((a), (b), (c), 0, 0, 0)
#define MFMA32(a, b, c) __builtin_amdgcn_mfma_f32_32x32x16_f16((a), (b), (c), 0, 0, 0)
#if __has_builtin(__builtin_amdgcn_exp2f)
#define EXP2(x) __builtin_amdgcn_exp2f(x)
#else
#define EXP2(x) exp2f(x)
#endif
#define GLLDS16(gp, lp)                                                    \
  __builtin_amdgcn_global_load_lds(                                        \
      (const __attribute__((address_space(1))) unsigned int*)(gp),         \
      (__attribute__((address_space(3))) unsigned int*)(lp), 16, 0, 0)

// log2(e) / sqrt(512)
#define QSCALE 0.0637587f

// ---------------------------------------- fused cvt: x -> f16, W^T -> f16
__global__ __launch_bounds__(256) void k_cvt(const float* __restrict__ x,
                                             f16* __restrict__ xb,
                                             const float* __restrict__ Wq,
                                             const float* __restrict__ Wk,
                                             const float* __restrict__ Wv,
                                             const float* __restrict__ Wo,
                                             f16* __restrict__ wt) {
  __shared__ float tl[32][33];
  const int bid = blockIdx.x;
  if (bid < 2048) {
    int i = bid * 256 + threadIdx.x;
    const float4* xp = (const float4*)x;
    f16x4* op = (f16x4*)xb;
    for (; i < 1048576; i += 524288) {
      float4 v = xp[i];
      f16x4 o = {(f16)v.x, (f16)v.y, (f16)v.z, (f16)v.w};
      op[i] = o;
    }
  } else {
    const int wi = bid - 2048;
    const int w = wi >> 8;
    const int bx = wi & 255;
    const float* W = (w == 0) ? Wq : (w == 1) ? Wk : (w == 2) ? Wv : Wo;
    const int j0 = (bx >> 4) * 32;
    const int k0 = (bx & 15) * 32;
    const int tx = threadIdx.x & 31, ty = threadIdx.x >> 5;
#pragma unroll
    for (int i = 0; i < 32; i += 8)
      tl[ty + i][tx] = W[(size_t)(k0 + ty + i) * 512 + j0 + tx];
    __syncthreads();
#pragma unroll
    for (int i = 0; i < 32; i += 8)
      wt[(size_t)w * 262144 + (size_t)(j0 + ty + i) * 512 + (k0 + tx)] =
          (f16)tl[tx][ty + i];
  }
}

// -------------------------------------------------------------- tiled GEMM
template <int BN, int MODE>
__global__ __launch_bounds__(256) void k_gemm(
    const f16* __restrict__ A, const f16* __restrict__ Wb3,
    const float* __restrict__ bias0, const float* __restrict__ bias1,
    const float* __restrict__ bias2, f16* __restrict__ oQ, f16* __restrict__ oK,
    f16* __restrict__ oV, float* __restrict__ oOut) {
  __shared__ __align__(16) f16 a_lds[128 * 64];
  __shared__ __align__(16) f16 b_lds[BN * 64];
  const int t = threadIdx.x;
  const int lane = t & 63, wid = t >> 6;
  const int l15 = lane & 15, l4 = lane >> 4;
  constexpr int MT = (BN == 128) ? 4 : 2;
  const int mbase = (BN == 128) ? (wid >> 1) * 64 : wid * 32;
  const int nbase = (BN == 128) ? (wid & 1) * 64 : 0;
  const int m0 = blockIdx.x * 128;
  const int by = blockIdx.y;
  const int wsel = (MODE == 0) ? (by >> 2) : 0;
  const int n0l = (MODE == 0) ? ((by & 3) * 128) : (by * (BN == 64 ? 64 : 128));
  const f16* Wt = Wb3 + (size_t)wsel * 262144;

  const int srow = t >> 3;
  const int sswz = ((t & 7) ^ (srow & 7)) * 8;
  const f16* Ag = A + (size_t)(m0 + srow) * 512 + sswz;
  const f16* Bg = Wt + (size_t)(n0l + srow) * 512 + sswz;

  f32x4 acc[MT][4];
  const f32x4 z4 = {0.f, 0.f, 0.f, 0.f};
#pragma unroll
  for (int i = 0; i < MT; i++)
#pragma unroll
    for (int j = 0; j < 4; j++) acc[i][j] = z4;

  for (int k0 = 0; k0 < 512; k0 += 64) {
#pragma unroll
    for (int i = 0; i < 4; i++)
      GLLDS16(Ag + (size_t)i * 16384 + k0, &a_lds[i * 2048 + wid * 512]);
#pragma unroll
    for (int i = 0; i < BN / 32; i++)
      GLLDS16(Bg + (size_t)i * 16384 + k0, &b_lds[i * 2048 + wid * 512]);
    __syncthreads();
#pragma unroll
    for (int ks = 0; ks < 2; ks++) {
      const int rs = ((ks * 4 + l4) ^ (l15 & 7)) * 8;
      f16x8 af[MT], bf[4];
#pragma unroll
      for (int mt = 0; mt < MT; mt++)
        af[mt] = *(const f16x8*)&a_lds[(mbase + mt * 16 + l15) * 64 + rs];
#pragma unroll
      for (int nt = 0; nt < 4; nt++)
        bf[nt] = *(const f16x8*)&b_lds[(nbase + nt * 16 + l15) * 64 + rs];
      __builtin_amdgcn_s_setprio(1);
#pragma unroll
      for (int mt = 0; mt < MT; mt++)
#pragma unroll
        for (int nt = 0; nt < 4; nt++)
          acc[mt][nt] = MFMA16(af[mt], bf[nt], acc[mt][nt]);
      __builtin_amdgcn_s_setprio(0);
    }
    __syncthreads();
  }

  if (MODE == 1) {
#pragma unroll
    for (int mt = 0; mt < MT; mt++)
#pragma unroll
      for (int nt = 0; nt < 4; nt++) {
        const int row = m0 + mbase + mt * 16 + l4 * 4;
        const int col = n0l + nbase + nt * 16 + l15;
        const float bv = bias0[col];
#pragma unroll
        for (int r = 0; r < 4; r++)
          oOut[(size_t)(row + r) * 512 + col] = acc[mt][nt][r] + bv;
      }
  } else {
#pragma unroll
    for (int mt = 0; mt < MT; mt++)
#pragma unroll
      for (int nt = 0; nt < 4; nt++) {
        const int colg = by * 128 + nbase + nt * 16 + l15;
        const int w = colg >> 9, jj = colg & 511;
        const int h = jj >> 6, d = jj & 63;
        const float* bp = (w == 0) ? bias0 : (w == 1) ? bias1 : bias2;
        const float bv = bp[jj];
        const float scl = (w == 0) ? QSCALE : 1.0f;
        const int rowg = m0 + mbase + mt * 16 + l4 * 4;
        const int b = rowg >> 11, nn = rowg & 2047;
        if (w == 2) {
          const size_t vb = ((size_t)(b * 8 + h) * 64 + d) * 2048 + nn;
          f16x4 vs;
#pragma unroll
          for (int r = 0; r < 4; r++) vs[r] = (f16)(acc[mt][nt][r] + bv);
          *(f16x4*)&oV[vb] = vs;
        } else {
          f16* op = (w == 0) ? oQ : oK;
          const size_t base = ((size_t)(b * 8 + h) * 2048 + nn) * 64 + d;
#pragma unroll
          for (int r = 0; r < 4; r++)
            op[base + (size_t)r * 64] = (f16)((acc[mt][nt][r] + bv) * scl);
        }
      }
  }
}

// ---------------------------------------------------------- flash attention
// 32x32x16 MFMA, chunk-XOR-swizzled subtiled LDS (2-way residual = free).
// grid 512 x 512 thr; bits[2:0]=XCD, [6:3]=q-block(16 of 128 rows),
// [8:7]=head-in-XCD. Wave w: s = w>>2 (kv half), w4 = w&3; wave owns 32
// q-rows x its half's 1024 kv in 16 kv-64 tiles. 4 waves/SIMD.
// LDS: K [kvt2][s4 4][kv32][2 chunk][8], chunk position p holds phys chunk
// p ^ ((kv>>2)&1) (write: pre-swizzled global source; read: rsw = hi ^
// ((l31>>2)&1)). Same for V [dt2][kb16 4][d32][2][8]. K rows pi-permuted
// (P(L): bits{0,1}<-L{0,1}, bit2<-L4, bit3<-L2, bit4<-L3) so P=exp2(scores)
// packs in-lane into the PV A-frags. Denominators: in-lane VALU sum +
// shfl_xor(32) + LDS inv table. Epilogue combines kv-halves via LDS.
__global__ __launch_bounds__(512, 4) void k_attn(const f16* __restrict__ Q,
                                                 const f16* __restrict__ K,
                                                 const f16* __restrict__ Vt,
                                                 f16* __restrict__ CTX) {
  __shared__ __align__(16) f16 k_lds[2][2][4096];  // [s][buf] 8KB tiles
  __shared__ __align__(16) f16 v_lds[2][2][4096];
  const int t = threadIdx.x, wid = t >> 6, lane = t & 63;
  const int l31 = lane & 31, hi = lane >> 5;
  const int s = wid >> 2, w4 = wid & 3;
  const int bid = blockIdx.x;
  const int bh = (bid & 7) * 4 + (bid >> 7);
  const int qb = (bid >> 3) & 15;
  const int q0 = qb * 128 + w4 * 32;
  const size_t kvb = (size_t)bh * (2048 * 64);
  const int kv0 = s * 1024;
  // read-side swizzled chunk offset (elems): phys chunk hi lives at
  // position hi ^ ((row>>2)&1) within row l31's 16-elem k/kv line.
  const int rsw = (hi ^ ((l31 >> 2) & 1)) * 8;

  // Q fragments (B-operand): lane holds col q = l31, k rows hi*8+j; 4 k-steps
  f16x8 qf[4];
#pragma unroll
  for (int s4 = 0; s4 < 4; s4++)
    qf[s4] =
        *(const f16x8*)&Q[kvb + (size_t)(q0 + l31) * 64 + s4 * 16 + hi * 8];

  f32x16 oa0, oa1;
  const f32x16 z16 = {0.f, 0.f, 0.f, 0.f, 0.f, 0.f, 0.f, 0.f,
                      0.f, 0.f, 0.f, 0.f, 0.f, 0.f, 0.f, 0.f};
  oa0 = z16;
  oa1 = z16;
  float lacc_s = 0.f;

  // ---- staging geometry (256 thr/half; tl = w4*64+lane; dest byte=tl*16):
  // K dest (issue i = kvt): s4=w4, kv_log=lane>>1, chunk-pos=tl&1 -> holds
  //   phys k-chunk (tl&1)^((lane>>3)&1); src row = kv0+kvt*32+P(kv_log),
  //   k = w4*16 + phys_chunk*8.  V analogous (d=lane>>1, kv-chunk swz).
  const int tl = w4 * 64 + lane;
  const int kvl = (tl >> 1) & 31;
  const int Pk = (kvl & 3) | (((kvl >> 4) & 1) << 2) | (((kvl >> 2) & 1) << 3) |
                 (((kvl >> 3) & 1) << 4);
  const int wsw = ((tl & 1) ^ ((lane >> 3) & 1)) * 8;  // write-side phys chunk
  const f16* Kg = K + kvb + (size_t)(kv0 + Pk) * 64 + w4 * 16 + wsw;
  const int dl = (tl >> 1) & 31;
  const f16* Vg = Vt + kvb + (size_t)dl * 2048 + kv0 + w4 * 16 + wsw;

  // ---- prologue: stage tile 0 into buffer 0
  {
    f16* kd = &k_lds[s][0][0] + tl * 8;
    f16* vd = &v_lds[s][0][0] + tl * 8;
    GLLDS16(Kg, kd);
    GLLDS16(Kg + 2048, kd + 2048);
    GLLDS16(Vg, vd);
    GLLDS16(Vg + 65536, vd + 2048);
  }
  __syncthreads();

  int cur = 0;
  for (int it = 0; it < 16; ++it) {
    if (it < 15) {
      const size_t ka = (size_t)(it + 1) * 4096;  // K: +64 phys rows
      const size_t va = (size_t)(it + 1) * 64;    // Vt: +64 n-cols
      f16* kd = &k_lds[s][cur ^ 1][0] + tl * 8;
      f16* vd = &v_lds[s][cur ^ 1][0] + tl * 8;
      GLLDS16(Kg + ka, kd);
      GLLDS16(Kg + ka + 2048, kd + 2048);
      GLLDS16(Vg + va, vd);
      GLLDS16(Vg + va + 65536, vd + 2048);
    }

    // ---- S^T = K Q^T (32x32x16): lane q=l31; kv = kvt*32 + crow(reg,hi)
    f32x16 st0 = z16, st1 = z16;
    const f16* kl = &k_lds[s][cur][0];
#pragma unroll
    for (int s4 = 0; s4 < 4; s4++) {
      const f16x8 kf0 = *(const f16x8*)&kl[s4 * 512 + l31 * 16 + rsw];
      const f16x8 kf1 = *(const f16x8*)&kl[2048 + s4 * 512 + l31 * 16 + rsw];
      __builtin_amdgcn_s_setprio(1);
      st0 = MFMA32(kf0, qf[s4], st0);
      st1 = MFMA32(kf1, qf[s4], st1);
      __builtin_amdgcn_s_setprio(0);
    }

    // ---- P = exp2(st); in-lane denominator sum; pack into PV A-frags
    float e0[16], e1[16];
#pragma unroll
    for (int r = 0; r < 16; r++) {
      e0[r] = EXP2(st0[r]);
      e1[r] = EXP2(st1[r]);
    }
    float sm = 0.f;
#pragma unroll
    for (int r = 0; r < 16; r++) sm += e0[r] + e1[r];
    lacc_s += sm;

    f16x8 pa00, pa01, pa10, pa11;
    {
      f16x2 c0, c1, c2, c3;
#define PK8(dst, e, w)                                                      \
      c0 = __builtin_bit_cast(                                              \
          f16x2, __builtin_amdgcn_cvt_pkrtz(e[4 * (w)], e[4 * (w) + 1]));   \
      c1 = __builtin_bit_cast(                                              \
          f16x2, __builtin_amdgcn_cvt_pkrtz(e[4 * (w) + 2], e[4 * (w) + 3]));\
      c2 = __builtin_bit_cast(                                              \
          f16x2, __builtin_amdgcn_cvt_pkrtz(e[4 * (w) + 8], e[4 * (w) + 9]));\
      c3 = __builtin_bit_cast(                                              \
          f16x2,                                                            \
          __builtin_amdgcn_cvt_pkrtz(e[4 * (w) + 10], e[4 * (w) + 11]));    \
      dst[0] = c0[0]; dst[1] = c0[1]; dst[2] = c1[0]; dst[3] = c1[1];       \
      dst[4] = c2[0]; dst[5] = c2[1]; dst[6] = c3[0]; dst[7] = c3[1];
      PK8(pa00, e0, 0)
      PK8(pa01, e0, 1)
      PK8(pa10, e1, 0)
      PK8(pa11, e1, 1)
#undef PK8
    }

    // ---- O += P V (32x32x16): vf subtile kb16 = kvt*2+w; dt = d-block
    const f16* vl = &v_lds[s][cur][0];
    const int vb = l31 * 16 + rsw;
    __builtin_amdgcn_s_setprio(1);
    oa0 = MFMA32(pa00, *(const f16x8*)&vl[vb], oa0);
    oa1 = MFMA32(pa00, *(const f16x8*)&vl[2048 + vb], oa1);
    oa0 = MFMA32(pa01, *(const f16x8*)&vl[512 + vb], oa0);
    oa1 = MFMA32(pa01, *(const f16x8*)&vl[2560 + vb], oa1);
    oa0 = MFMA32(pa10, *(const f16x8*)&vl[1024 + vb], oa0);
    oa1 = MFMA32(pa10, *(const f16x8*)&vl[3072 + vb], oa1);
    oa0 = MFMA32(pa11, *(const f16x8*)&vl[1536 + vb], oa0);
    oa1 = MFMA32(pa11, *(const f16x8*)&vl[3584 + vb], oa1);
    __builtin_amdgcn_s_setprio(0);
    __syncthreads();
    cur ^= 1;
  }

  // complete this half's denominator: lane's regs cover half the kv rows
  lacc_s += __shfl_xor(lacc_s, 32);

  // ---- epilogue: combine halves via LDS (SoA [elem][thread])
  float* so = (float*)&k_lds[0][0][0];  // 32*256 f32 = 32KB (exact)
  float* sl = (float*)&v_lds[0][0][0];  // 256 f32
  float* linv = ((float*)&v_lds[0][0][0]) + 256;  // 128 f32
  const int ln = w4 * 64 + lane;
  if (s == 1) {
#pragma unroll
    for (int r = 0; r < 16; r++) {
      so[r * 256 + ln] = oa0[r];
      so[(16 + r) * 256 + ln] = oa1[r];
    }
    sl[ln] = lacc_s;
  }
  __syncthreads();
  if (s == 0) {
    const float ltot = lacc_s + sl[ln];
    if (lane < 32) linv[w4 * 32 + l31] = 1.0f / ltot;
    const int b = bh >> 3, h = bh & 7;
#pragma unroll
    for (int r = 0; r < 16; r++) {
      const int qrow = q0 + (r & 3) + 8 * (r >> 2) + 4 * hi;
      const float inv = linv[w4 * 32 + ((r & 3) + 8 * (r >> 2) + 4 * hi)];
      const float v0 = oa0[r] + so[r * 256 + ln];
      const float v1 = oa1[r] + so[(16 + r) * 256 + ln];
      const size_t rb = (size_t)(b * 2048 + qrow) * 512 + h * 64;
      CTX[rb + l31] = (f16)(v0 * inv);
      CTX[rb + 32 + l31] = (f16)(v1 * inv);
    }
  }
}

// ----------------------------------------------------------------- launcher
extern "C" void kernel_launch(void* const* d_in, const int* in_sizes, int n_in,
                              void* d_out, int out_size, void* d_ws,
                              size_t ws_size, hipStream_t stream) {
  const float* x = (const float*)d_in[0];
  const float* Wq = (const float*)d_in[1];
  const float* bq = (const float*)d_in[2];
  const float* Wk = (const float*)d_in[3];
  const float* bk = (const float*)d_in[4];
  const float* Wv = (const float*)d_in[5];
  const float* bv = (const float*)d_in[6];
  const float* Wo = (const float*)d_in[7];
  const float* bo = (const float*)d_in[8];
  float* out = (float*)d_out;
  char* ws = (char*)d_ws;

  f16* xb = (f16*)(ws);                        // 8 MB
  f16* wt = (f16*)(ws + (size_t)(8u << 20));   // 2 MB  [4][512][512]
  f16* Qb = (f16*)(ws + (size_t)(10u << 20));  // 8 MB  [B][H][N][D]
  f16* Kb = (f16*)(ws + (size_t)(18u << 20));  // 8 MB  [B][H][N][D]
  f16* Vt = (f16*)(ws + (size_t)(26u << 20));  // 8 MB  [B][H][D][N]
  f16* CX = (f16*)(ws + (size_t)(34u << 20));  // 8 MB  [B][N][F]

  k_cvt<<<dim3(3072), dim3(256), 0, stream>>>(x, xb, Wq, Wk, Wv, Wo, wt);
  k_gemm<128, 0><<<dim3(64, 12), dim3(256), 0, stream>>>(
      xb, wt, bq, bk, bv, Qb, Kb, Vt, nullptr);
  k_attn<<<dim3(512), dim3(512), 0, stream>>>(Qb, Kb, Vt, CX);
  k_gemm<64, 1><<<dim3(64, 8), dim3(256), 0, stream>>>(
      CX, wt + (size_t)3 * 262144, bo, nullptr, nullptr, nullptr, nullptr,
      nullptr, out);
}

// Round 18
// 79.814 us; speedup vs baseline: 1.0527x; 1.0527x over previous
//
#include <hip/hip_runtime.h>

// MultiHeadSelfAttention: B=4 N=2048 F=512 H=8 D=64, scale = 1/sqrt(512)
// Pipeline: fused cvt (x->f16 + W^T->f16, ONE dispatch), fused QKV GEMM
// (mfma f16, gload_lds staging, Q pre-scaled by log2e/sqrt(512), V stored
// TRANSPOSED [B][H][D][N] with vectorized f16x4 epilogue stores), flash
// attention with IN-BLOCK KV-SPLIT (512-thr blocks; waves 0-3 kv 0-1023,
// waves 4-7 kv 1024-2047 for the same 128 q-rows; 2 blocks/CU x 8 waves =
// 4 waves/SIMD; fp32 partials combined through LDS at epilogue), output GEMM
// (128x64, fp32+bias).  [R15 configuration -- best measured: 80.4 us]
// ws: xb@0 | wt@8MB | Q@10MB K@18MB Vt@26MB | CX@34MB.

typedef _Float16 f16;
typedef _Float16 f16x2 __attribute__((ext_vector_type(2)));
typedef _Float16 f16x4 __attribute__((ext_vector_type(4)));
typedef _Float16 f16x8 __attribute__((ext_vector_type(8)));
typedef float f32x4 __attribute__((ext_vector_type(4)));

#define MFMA16(a, b, c) __builtin_amdgcn_mfma_f32_16x16x32_f16((a), (b), (c), 0, 0, 0)
#if __has_builtin(__builtin_amdgcn_exp2f)
#define EXP2(x) __builtin_amdgcn_exp2f(x)
#else
#define EXP2(x) exp2f(x)
#endif
#define GLLDS16(gp, lp)                                                    \
  __builtin_amdgcn_global_load_lds(                                        \
      (const __attribute__((address_space(1))) unsigned int*)(gp),         \
      (__attribute__((address_space(3))) unsigned int*)(lp), 16, 0, 0)

// log2(e) / sqrt(512)
#define QSCALE 0.0637587f

// ---------------------------------------- fused cvt: x -> f16, W^T -> f16
// grid 3072 x 256: blocks 0..2047 convert x (grid-stride float4->f16x4);
// blocks 2048..3071 transpose-convert one 32x32 tile of one W matrix.
__global__ __launch_bounds__(256) void k_cvt(const float* __restrict__ x,
                                             f16* __restrict__ xb,
                                             const float* __restrict__ Wq,
                                             const float* __restrict__ Wk,
                                             const float* __restrict__ Wv,
                                             const float* __restrict__ Wo,
                                             f16* __restrict__ wt) {
  __shared__ float tl[32][33];
  const int bid = blockIdx.x;
  if (bid < 2048) {
    int i = bid * 256 + threadIdx.x;
    const float4* xp = (const float4*)x;
    f16x4* op = (f16x4*)xb;
    for (; i < 1048576; i += 524288) {
      float4 v = xp[i];
      f16x4 o = {(f16)v.x, (f16)v.y, (f16)v.z, (f16)v.w};
      op[i] = o;
    }
  } else {
    const int wi = bid - 2048;
    const int w = wi >> 8;
    const int bx = wi & 255;
    const float* W = (w == 0) ? Wq : (w == 1) ? Wk : (w == 2) ? Wv : Wo;
    const int j0 = (bx >> 4) * 32;
    const int k0 = (bx & 15) * 32;
    const int tx = threadIdx.x & 31, ty = threadIdx.x >> 5;
#pragma unroll
    for (int i = 0; i < 32; i += 8)
      tl[ty + i][tx] = W[(size_t)(k0 + ty + i) * 512 + j0 + tx];
    __syncthreads();
#pragma unroll
    for (int i = 0; i < 32; i += 8)
      wt[(size_t)w * 262144 + (size_t)(j0 + ty + i) * 512 + (k0 + tx)] =
          (f16)tl[tx][ty + i];
  }
}

// -------------------------------------------------------------- tiled GEMM
// 128 x BN tiles, K-step 64, gload_lds staging (lane-linear LDS dest,
// XOR-swizzled per-lane global source), single-buffer 2-barrier (m97).
// MODE 0 (BN=128): out -> Q/K f16 [B][H][N][D], V TRANSPOSED [B][H][D][N]
//                  (f16x4 vector store); + bias; Q scaled by QSCALE. (64,12)
// MODE 1 (BN=64):  out -> float [M][512] + bias.  grid (64, 8).
template <int BN, int MODE>
__global__ __launch_bounds__(256) void k_gemm(
    const f16* __restrict__ A, const f16* __restrict__ Wb3,
    const float* __restrict__ bias0, const float* __restrict__ bias1,
    const float* __restrict__ bias2, f16* __restrict__ oQ, f16* __restrict__ oK,
    f16* __restrict__ oV, float* __restrict__ oOut) {
  __shared__ __align__(16) f16 a_lds[128 * 64];
  __shared__ __align__(16) f16 b_lds[BN * 64];
  const int t = threadIdx.x;
  const int lane = t & 63, wid = t >> 6;
  const int l15 = lane & 15, l4 = lane >> 4;
  constexpr int MT = (BN == 128) ? 4 : 2;
  const int mbase = (BN == 128) ? (wid >> 1) * 64 : wid * 32;
  const int nbase = (BN == 128) ? (wid & 1) * 64 : 0;
  const int m0 = blockIdx.x * 128;
  const int by = blockIdx.y;
  const int wsel = (MODE == 0) ? (by >> 2) : 0;
  const int n0l = (MODE == 0) ? ((by & 3) * 128) : (by * (BN == 64 ? 64 : 128));
  const f16* Wt = Wb3 + (size_t)wsel * 262144;

  const int srow = t >> 3;                      // 0..31
  const int sswz = ((t & 7) ^ (srow & 7)) * 8;  // swizzled k-offset
  const f16* Ag = A + (size_t)(m0 + srow) * 512 + sswz;
  const f16* Bg = Wt + (size_t)(n0l + srow) * 512 + sswz;

  f32x4 acc[MT][4];
  const f32x4 z4 = {0.f, 0.f, 0.f, 0.f};
#pragma unroll
  for (int i = 0; i < MT; i++)
#pragma unroll
    for (int j = 0; j < 4; j++) acc[i][j] = z4;

  for (int k0 = 0; k0 < 512; k0 += 64) {
#pragma unroll
    for (int i = 0; i < 4; i++)
      GLLDS16(Ag + (size_t)i * 16384 + k0, &a_lds[i * 2048 + wid * 512]);
#pragma unroll
    for (int i = 0; i < BN / 32; i++)
      GLLDS16(Bg + (size_t)i * 16384 + k0, &b_lds[i * 2048 + wid * 512]);
    __syncthreads();
#pragma unroll
    for (int ks = 0; ks < 2; ks++) {
      const int rs = ((ks * 4 + l4) ^ (l15 & 7)) * 8;
      f16x8 af[MT], bf[4];
#pragma unroll
      for (int mt = 0; mt < MT; mt++)
        af[mt] = *(const f16x8*)&a_lds[(mbase + mt * 16 + l15) * 64 + rs];
#pragma unroll
      for (int nt = 0; nt < 4; nt++)
        bf[nt] = *(const f16x8*)&b_lds[(nbase + nt * 16 + l15) * 64 + rs];
      __builtin_amdgcn_s_setprio(1);
#pragma unroll
      for (int mt = 0; mt < MT; mt++)
#pragma unroll
        for (int nt = 0; nt < 4; nt++)
          acc[mt][nt] = MFMA16(af[mt], bf[nt], acc[mt][nt]);
      __builtin_amdgcn_s_setprio(0);
    }
    __syncthreads();
  }

  if (MODE == 1) {
#pragma unroll
    for (int mt = 0; mt < MT; mt++)
#pragma unroll
      for (int nt = 0; nt < 4; nt++) {
        const int row = m0 + mbase + mt * 16 + l4 * 4;
        const int col = n0l + nbase + nt * 16 + l15;
        const float bv = bias0[col];
#pragma unroll
        for (int r = 0; r < 4; r++)
          oOut[(size_t)(row + r) * 512 + col] = acc[mt][nt][r] + bv;
      }
  } else {
#pragma unroll
    for (int mt = 0; mt < MT; mt++)
#pragma unroll
      for (int nt = 0; nt < 4; nt++) {
        const int colg = by * 128 + nbase + nt * 16 + l15;
        const int w = colg >> 9, jj = colg & 511;
        const int h = jj >> 6, d = jj & 63;
        const float* bp = (w == 0) ? bias0 : (w == 1) ? bias1 : bias2;
        const float bv = bp[jj];
        const float scl = (w == 0) ? QSCALE : 1.0f;  // fold softmax scale into Q
        const int rowg = m0 + mbase + mt * 16 + l4 * 4;
        const int b = rowg >> 11, nn = rowg & 2047;
        if (w == 2) {
          // V transposed: Vt[((b*8+h)*64 + d)*2048 + n]; 4 consecutive n ->
          // one 8B f16x4 store (rowg % 4 == 0 so vb is 8B-aligned).
          const size_t vb = ((size_t)(b * 8 + h) * 64 + d) * 2048 + nn;
          f16x4 vs;
#pragma unroll
          for (int r = 0; r < 4; r++) vs[r] = (f16)(acc[mt][nt][r] + bv);
          *(f16x4*)&oV[vb] = vs;
        } else {
          f16* op = (w == 0) ? oQ : oK;
          const size_t base = ((size_t)(b * 8 + h) * 2048 + nn) * 64 + d;
#pragma unroll
          for (int r = 0; r < 4; r++)
            op[base + (size_t)r * 64] = (f16)((acc[mt][nt][r] + bv) * scl);
        }
      }
  }
}

// ---------------------------------------------------------- flash attention
// IN-BLOCK KV-SPLIT: grid 512 x 512 thr. bits[2:0]=XCD, [6:3]=q-block(16 of
// 128 rows), [8:7]=head-in-XCD. Wave w: s = w>>2 (kv half), w4 = w&3; wave
// owns 32 q-rows (2 q-sets of 16) x its half's 1024 kv in 16 kv-64 tiles.
// 2 blocks/CU x 8 waves = 4 waves/SIMD. Per-half double-buffered LDS (64KB
// total/block), 1 barrier/tile (both halves in lockstep cadence).
// K staged with pi row-permutation + XOR swizzle; Vt staged [64d][64kv].
// Swapped QK^T; P = exp2(st) in-register -> K32 PV A-frags by pure concat;
// denominators via ones-MFMA. Epilogue: half-1 publishes fp32 partials via
// LDS (SoA, conflict-free), half-0 combines, normalizes, writes CTX.
__global__ __launch_bounds__(512, 4) void k_attn(const f16* __restrict__ Q,
                                                 const f16* __restrict__ K,
                                                 const f16* __restrict__ Vt,
                                                 f16* __restrict__ CTX) {
  __shared__ __align__(16) f16 k_lds[2][2][4096];  // [s][buf]
  __shared__ __align__(16) f16 v_lds[2][2][4096];
  const int t = threadIdx.x, wid = t >> 6, lane = t & 63;
  const int l15 = lane & 15, l4 = lane >> 4;
  const int s = wid >> 2, w4 = wid & 3;
  const int bid = blockIdx.x;
  const int bh = (bid & 7) * 4 + (bid >> 7);
  const int qb = (bid >> 3) & 15;
  const int q0 = qb * 128 + w4 * 32;
  const size_t kvb = (size_t)bh * (2048 * 64);
  const int kv0 = s * 1024;  // this half's KV range

  // Q fragments (B-operand of swapped QK^T), 2 q-sets
  f16x8 qf[2][2];
#pragma unroll
  for (int g = 0; g < 2; g++)
#pragma unroll
    for (int ks = 0; ks < 2; ks++)
      qf[g][ks] = *(const f16x8*)&Q[kvb + (size_t)(q0 + g * 16 + l15) * 64 +
                                    ks * 32 + l4 * 8];

  f32x4 oa[2][4];
  f32x4 lacc[2];
  const f32x4 z4 = {0.f, 0.f, 0.f, 0.f};
#pragma unroll
  for (int g = 0; g < 2; g++) {
    lacc[g] = z4;
#pragma unroll
    for (int dt = 0; dt < 4; dt++) oa[g][dt] = z4;
  }
  const f16 one = (f16)1.0f;
  const f16x8 ones = {one, one, one, one, one, one, one, one};

  // staging geometry (per half): LDS elem E = issue*2048 + w4*512 + lane*8;
  // K logical row L = issue*32 + krow -> stage phys pi(L) (pi passes bit5,
  // so issue 1 = +2048 is pi-consistent); V row d = L.
  const int krow = w4 * 8 + (lane >> 3);
  const int kswz = ((lane & 7) ^ (lane >> 3)) * 8;
  const int kperm = ((krow & 0x0C) << 1) | ((krow & 0x10) >> 2) | (krow & 3);
  const f16* Kg = K + kvb + (size_t)(kv0 + kperm) * 64 + kswz;
  const f16* Vg = Vt + kvb + (size_t)krow * 2048 + kv0 + kswz;

  // ---- prologue: stage this half's tile 0 into buffer 0
  GLLDS16(Kg, &k_lds[s][0][w4 * 512]);
  GLLDS16(Kg + 2048, &k_lds[s][0][w4 * 512 + 2048]);
  GLLDS16(Vg, &v_lds[s][0][w4 * 512]);
  GLLDS16(Vg + 32 * 2048, &v_lds[s][0][w4 * 512 + 2048]);
  __syncthreads();

  int cur = 0;
  for (int it = 0; it < 16; ++it) {
    if (it < 15) {
      const size_t kb = (size_t)(it + 1) * 4096;  // K advances 64 rows
      const size_t vb = (size_t)(it + 1) * 64;    // Vt advances 64 cols
      GLLDS16(Kg + kb, &k_lds[s][cur ^ 1][w4 * 512]);
      GLLDS16(Kg + kb + 2048, &k_lds[s][cur ^ 1][w4 * 512 + 2048]);
      GLLDS16(Vg + vb, &v_lds[s][cur ^ 1][w4 * 512]);
      GLLDS16(Vg + vb + 32 * 2048, &v_lds[s][cur ^ 1][w4 * 512 + 2048]);
    }

    // ---- S^T = K Q^T: lane holds st[g][w][r] = S[q=l15][kv_log=w*16+l4*4+r]
    f32x4 st[2][4];
#pragma unroll
    for (int g = 0; g < 2; g++)
#pragma unroll
      for (int w = 0; w < 4; w++) st[g][w] = z4;
    const f16* kl = &k_lds[s][cur][0];
#pragma unroll
    for (int ks = 0; ks < 2; ks++) {
      const int rs = ((ks * 4 + l4) ^ (l15 & 7)) * 8;
      f16x8 kf[4];
#pragma unroll
      for (int w = 0; w < 4; w++)
        kf[w] = *(const f16x8*)&kl[(w * 16 + l15) * 64 + rs];
      __builtin_amdgcn_s_setprio(1);
#pragma unroll
      for (int w = 0; w < 4; w++) {
        st[0][w] = MFMA16(kf[w], qf[0][ks], st[0][w]);
        st[1][w] = MFMA16(kf[w], qf[1][ks], st[1][w]);
      }
      __builtin_amdgcn_s_setprio(0);
    }

    // ---- P = exp2(st) packed straight into K32 PV A-frags (pi-aligned)
    f16x8 pa[2][2];
#pragma unroll
    for (int g = 0; g < 2; g++)
#pragma unroll
      for (int ks = 0; ks < 2; ks++) {
        f16x2 a0 = __builtin_bit_cast(
            f16x2, __builtin_amdgcn_cvt_pkrtz(EXP2(st[g][2 * ks][0]),
                                              EXP2(st[g][2 * ks][1])));
        f16x2 a1 = __builtin_bit_cast(
            f16x2, __builtin_amdgcn_cvt_pkrtz(EXP2(st[g][2 * ks][2]),
                                              EXP2(st[g][2 * ks][3])));
        f16x2 a2 = __builtin_bit_cast(
            f16x2, __builtin_amdgcn_cvt_pkrtz(EXP2(st[g][2 * ks + 1][0]),
                                              EXP2(st[g][2 * ks + 1][1])));
        f16x2 a3 = __builtin_bit_cast(
            f16x2, __builtin_amdgcn_cvt_pkrtz(EXP2(st[g][2 * ks + 1][2]),
                                              EXP2(st[g][2 * ks + 1][3])));
        f16x8 p;
        p[0] = a0[0]; p[1] = a0[1]; p[2] = a1[0]; p[3] = a1[1];
        p[4] = a2[0]; p[5] = a2[1]; p[6] = a3[0]; p[7] = a3[1];
        pa[g][ks] = p;
      }

    // ---- O += P V (K32), l += P 1 (ones-MFMA); vf shared across q-sets
    const f16* vl = &v_lds[s][cur][0];
#pragma unroll
    for (int ks = 0; ks < 2; ks++) {
      __builtin_amdgcn_s_setprio(1);
      lacc[0] = MFMA16(pa[0][ks], ones, lacc[0]);
      lacc[1] = MFMA16(pa[1][ks], ones, lacc[1]);
#pragma unroll
      for (int dt = 0; dt < 4; dt++) {
        const f16x8 vf = *(const f16x8*)&vl[(dt * 16 + l15) * 64 +
                                            ((ks * 4 + l4) ^ (l15 & 7)) * 8];
        oa[0][dt] = MFMA16(pa[0][ks], vf, oa[0][dt]);
        oa[1][dt] = MFMA16(pa[1][ks], vf, oa[1][dt]);
      }
      __builtin_amdgcn_s_setprio(0);
    }
    __syncthreads();
    cur ^= 1;
  }

  // ---- epilogue: combine halves via LDS (SoA [elem][thread], conflict-free)
  float* so = (float*)&k_lds[0][0][0];
  float* sl = (float*)&v_lds[0][0][0];
  const int ln = w4 * 64 + lane;  // 0..255
  if (s == 1) {
#pragma unroll
    for (int g = 0; g < 2; g++) {
#pragma unroll
      for (int dt = 0; dt < 4; dt++)
#pragma unroll
        for (int r = 0; r < 4; r++)
          so[(g * 16 + dt * 4 + r) * 256 + ln] = oa[g][dt][r];
#pragma unroll
      for (int r = 0; r < 4; r++) sl[(g * 4 + r) * 256 + ln] = lacc[g][r];
    }
  }
  __syncthreads();
  if (s == 0) {
    const int b = bh >> 3, h = bh & 7;
#pragma unroll
    for (int g = 0; g < 2; g++) {
#pragma unroll
      for (int r = 0; r < 4; r++) {
        const float lt = lacc[g][r] + sl[(g * 4 + r) * 256 + ln];
        const float inv = 1.0f / lt;
        const int qrow = q0 + g * 16 + l4 * 4 + r;
#pragma unroll
        for (int dt = 0; dt < 4; dt++) {
          const float ov =
              oa[g][dt][r] + so[(g * 16 + dt * 4 + r) * 256 + ln];
          CTX[(size_t)(b * 2048 + qrow) * 512 + h * 64 + dt * 16 + l15] =
              (f16)(ov * inv);
        }
      }
    }
  }
}

// ----------------------------------------------------------------- launcher
extern "C" void kernel_launch(void* const* d_in, const int* in_sizes, int n_in,
                              void* d_out, int out_size, void* d_ws,
                              size_t ws_size, hipStream_t stream) {
  const float* x = (const float*)d_in[0];
  const float* Wq = (const float*)d_in[1];
  const float* bq = (const float*)d_in[2];
  const float* Wk = (const float*)d_in[3];
  const float* bk = (const float*)d_in[4];
  const float* Wv = (const float*)d_in[5];
  const float* bv = (const float*)d_in[6];
  const float* Wo = (const float*)d_in[7];
  const float* bo = (const float*)d_in[8];
  float* out = (float*)d_out;
  char* ws = (char*)d_ws;

  f16* xb = (f16*)(ws);                        // 8 MB
  f16* wt = (f16*)(ws + (size_t)(8u << 20));   // 2 MB  [4][512][512]
  f16* Qb = (f16*)(ws + (size_t)(10u << 20));  // 8 MB  [B][H][N][D]
  f16* Kb = (f16*)(ws + (size_t)(18u << 20));  // 8 MB  [B][H][N][D]
  f16* Vt = (f16*)(ws + (size_t)(26u << 20));  // 8 MB  [B][H][D][N]
  f16* CX = (f16*)(ws + (size_t)(34u << 20));  // 8 MB  [B][N][F]

  k_cvt<<<dim3(3072), dim3(256), 0, stream>>>(x, xb, Wq, Wk, Wv, Wo, wt);
  k_gemm<128, 0><<<dim3(64, 12), dim3(256), 0, stream>>>(
      xb, wt, bq, bk, bv, Qb, Kb, Vt, nullptr);
  k_attn<<<dim3(512), dim3(512), 0, stream>>>(Qb, Kb, Vt, CX);
  k_gemm<64, 1><<<dim3(64, 8), dim3(256), 0, stream>>>(
      CX, wt + (size_t)3 * 262144, bo, nullptr, nullptr, nullptr, nullptr,
      nullptr, out);
}